// Round 1
// baseline (465.007 us; speedup 1.0000x reference)
//
#include <hip/hip_runtime.h>
#include <math.h>

#define B_   256
#define S_   512
#define NQ_  1000
#define MEM_ 20
#define DK_  50
#define DV_  200
#define FC_  50
#define RPB  8

static __device__ __forceinline__ unsigned short f2bf(float f){
  unsigned u = __float_as_uint(f);
  unsigned r = u + 0x7fffu + ((u >> 16) & 1u);   // round-to-nearest-even
  return (unsigned short)(r >> 16);
}
static __device__ __forceinline__ float bfhi(unsigned v){ return __uint_as_float(v & 0xffff0000u); }
static __device__ __forceinline__ float bflo(unsigned v){ return __uint_as_float(v << 16); }

// K1: corrTab[q][m] = softmax_m( q_embed_w[q] . memory_key[m] )
__global__ void k_corr(const float* __restrict__ qw, const float* __restrict__ mk,
                       float* __restrict__ corrTab){
  int q = blockIdx.x*blockDim.x + threadIdx.x;
  if(q > NQ_) return;
  float qv[DK_];
  #pragma unroll
  for(int j=0;j<DK_;++j) qv[j] = qw[q*DK_+j];
  float s[MEM_]; float mx = -1e30f;
  #pragma unroll
  for(int m=0;m<MEM_;++m){
    float acc = 0.f;
    #pragma unroll
    for(int j=0;j<DK_;++j) acc = fmaf(qv[j], mk[m*DK_+j], acc);
    s[m] = acc; mx = fmaxf(mx, acc);
  }
  float sum = 0.f;
  #pragma unroll
  for(int m=0;m<MEM_;++m){ s[m] = expf(s[m]-mx); sum += s[m]; }
  float inv = 1.f/sum;
  #pragma unroll
  for(int m=0;m<MEM_;++m) corrTab[q*MEM_+m] = s[m]*inv;
}

// K2: eraseTab[qa] = sigmoid(qa_e @ erase_w + eb), addTab[qa] = tanh(qa_e @ add_w + ab)
// 8 qa-rows per block so each W element load serves 8 rows.
__global__ __launch_bounds__(256) void k_ea(const float* __restrict__ qaw,
      const float* __restrict__ ew, const float* __restrict__ eb,
      const float* __restrict__ aw, const float* __restrict__ ab,
      float* __restrict__ eraseTab, float* __restrict__ addTab){
  __shared__ float qa[RPB][DV_];
  int row0 = blockIdx.x*RPB;
  for(int i=threadIdx.x; i<RPB*DV_; i+=256){
    int r = i/DV_, c = i - r*DV_;
    int row = row0 + r;
    qa[r][c] = (row <= 2*NQ_) ? qaw[row*DV_+c] : 0.f;
  }
  __syncthreads();
  int d = threadIdx.x;
  if(d >= DV_) return;
  float accE[RPB], accA[RPB];
  #pragma unroll
  for(int r=0;r<RPB;++r){ accE[r] = eb[d]; accA[r] = ab[d]; }
  for(int j=0;j<DV_;++j){
    float we = ew[j*DV_+d], wa = aw[j*DV_+d];
    #pragma unroll
    for(int r=0;r<RPB;++r){
      float x = qa[r][j];
      accE[r] = fmaf(x, we, accE[r]);
      accA[r] = fmaf(x, wa, accA[r]);
    }
  }
  #pragma unroll
  for(int r=0;r<RPB;++r){
    int row = row0 + r;
    if(row <= 2*NQ_){
      eraseTab[row*DV_+d] = 1.f/(1.f+expf(-accE[r]));
      addTab[row*DV_+d]   = tanhf(accA[r]);
    }
  }
}

// K3: the true recurrence. One block per batch element, thread d owns Mv[0..19][d]
// in registers. q/qa staged in LDS; next-step e/a/corr prefetched (1-deep pipeline).
__global__ __launch_bounds__(256) void k_scan(const int* __restrict__ qd,
    const int* __restrict__ qad,
    const float* __restrict__ corrTab,
    const float* __restrict__ eraseTab,
    const float* __restrict__ addTab,
    const float* __restrict__ mv0,
    unsigned short* __restrict__ reads){
  int b = blockIdx.x;
  int d = threadIdx.x;
  __shared__ int sq[S_];
  __shared__ int sqa[S_];
  for(int t=threadIdx.x; t<S_; t+=256){
    sq[t]  = qd[b*S_+t];
    sqa[t] = qad[b*S_+t];
  }
  __syncthreads();
  if(d >= DV_) return;
  float Mv[MEM_];
  #pragma unroll
  for(int m=0;m<MEM_;++m) Mv[m] = mv0[m*DV_+d];

  int q0  = __builtin_amdgcn_readfirstlane(sq[0]);
  int qa0 = __builtin_amdgcn_readfirstlane(sqa[0]);
  float e = eraseTab[qa0*DV_+d];
  float a = addTab[qa0*DV_+d];
  float c[MEM_];
  #pragma unroll
  for(int m=0;m<MEM_;++m) c[m] = corrTab[q0*MEM_+m];

  size_t outbase = (size_t)b*S_*DV_ + d;
  for(int t=0;t<S_;++t){
    int tn  = (t+1 < S_) ? t+1 : t;
    int qn  = __builtin_amdgcn_readfirstlane(sq[tn]);
    int qan = __builtin_amdgcn_readfirstlane(sqa[tn]);
    float en = eraseTab[qan*DV_+d];
    float an = addTab[qan*DV_+d];
    float cn[MEM_];
    #pragma unroll
    for(int m=0;m<MEM_;++m) cn[m] = corrTab[qn*MEM_+m];

    float rd = 0.f;
    #pragma unroll
    for(int m=0;m<MEM_;++m){
      rd    = fmaf(c[m], Mv[m], rd);                      // read uses pre-update Mv
      Mv[m] = fmaf(c[m], fmaf(-Mv[m], e, a), Mv[m]);      // Mv += c*(a - Mv*e)
    }
    reads[outbase + (size_t)t*DV_] = f2bf(rd);
    e = en; a = an;
    #pragma unroll
    for(int m=0;m<MEM_;++m) c[m] = cn[m];
  }
}

// K4: h = tanh([reads, q_e] @ read_w + rb); logit = h @ pw + pb; prob + masked BCE.
// thread = row; 50 fp32 accumulators; read_w accesses are wave-uniform -> SGPR path.
__global__ __launch_bounds__(256) void k_out(
    const unsigned short* __restrict__ reads,
    const int* __restrict__ qd,
    const float* __restrict__ qw,
    const float* __restrict__ rw, const float* __restrict__ rb,
    const float* __restrict__ pw, const float* __restrict__ pb,
    const float* __restrict__ target,
    float* __restrict__ out, float* __restrict__ accum){
  int row = blockIdx.x*256 + threadIdx.x;
  float acc[FC_];
  #pragma unroll
  for(int f=0;f<FC_;++f) acc[f] = rb[f];

  const uint4* xp = reinterpret_cast<const uint4*>(reads + (size_t)row*DV_);
  uint4 v = xp[0];
  #pragma unroll 1
  for(int blk=0; blk<DV_/8; ++blk){
    uint4 vn = xp[(blk+1 < DV_/8) ? blk+1 : blk];   // prefetch next 8 bf16
    float xv[8];
    xv[0]=bflo(v.x); xv[1]=bfhi(v.x); xv[2]=bflo(v.y); xv[3]=bfhi(v.y);
    xv[4]=bflo(v.z); xv[5]=bfhi(v.z); xv[6]=bflo(v.w); xv[7]=bfhi(v.w);
    const float* wb = rw + blk*8*FC_;
    #pragma unroll
    for(int k=0;k<8;++k){
      float xk = xv[k];
      const float* wr = wb + k*FC_;
      #pragma unroll
      for(int f=0;f<FC_;++f) acc[f] = fmaf(xk, wr[f], acc[f]);
    }
    v = vn;
  }

  int q = qd[row];
  const float2* qe2 = reinterpret_cast<const float2*>(qw + q*DK_);
  #pragma unroll 1
  for(int j2=0;j2<DK_/2;++j2){
    float2 x2 = qe2[j2];
    const float* wr = rw + (DV_ + 2*j2)*FC_;
    #pragma unroll
    for(int f=0;f<FC_;++f) acc[f] = fmaf(x2.x, wr[f], acc[f]);
    #pragma unroll
    for(int f=0;f<FC_;++f) acc[f] = fmaf(x2.y, wr[FC_+f], acc[f]);
  }

  float logit = pb[0];
  #pragma unroll
  for(int f=0;f<FC_;++f) logit = fmaf(pw[f], tanhf(acc[f]), logit);

  float prob = 1.f/(1.f+expf(-logit));
  out[1+row] = prob;

  float t = target[row];
  float bce = 0.f, cnt = 0.f;
  if(t >= 0.f){
    cnt = 1.f;
    bce = fmaxf(logit,0.f) - logit*t + log1pf(expf(-fabsf(logit)));
  }
  #pragma unroll
  for(int off=32; off>0; off>>=1){
    bce += __shfl_down(bce, off, 64);
    cnt += __shfl_down(cnt, off, 64);
  }
  if((threadIdx.x & 63) == 0){
    atomicAdd(accum,   bce);
    atomicAdd(accum+1, cnt);
  }
}

__global__ void k_fin(const float* __restrict__ accum, float* __restrict__ out){
  out[0] = accum[0] / fmaxf(accum[1], 1.f);
}

extern "C" void kernel_launch(void* const* d_in, const int* in_sizes, int n_in,
                              void* d_out, int out_size, void* d_ws, size_t ws_size,
                              hipStream_t stream){
  const int*   qd     = (const int*)d_in[0];
  const int*   qad    = (const int*)d_in[1];
  const float* target = (const float*)d_in[2];
  const float* qw     = (const float*)d_in[3];
  const float* qaw    = (const float*)d_in[4];
  const float* mk     = (const float*)d_in[5];
  const float* mv0    = (const float*)d_in[6];
  const float* ew     = (const float*)d_in[7];
  const float* eb     = (const float*)d_in[8];
  const float* aw     = (const float*)d_in[9];
  const float* ab     = (const float*)d_in[10];
  const float* rw     = (const float*)d_in[11];
  const float* rb     = (const float*)d_in[12];
  const float* pw     = (const float*)d_in[13];
  const float* pb     = (const float*)d_in[14];
  float* out = (float*)d_out;

  char* ws = (char*)d_ws;
  size_t off = 0;
  float* accum = (float*)(ws + off);                 off += 256;
  float* corrTab  = (float*)(ws + off);              off += (((size_t)(NQ_+1)*MEM_*4 + 255)/256)*256;
  float* eraseTab = (float*)(ws + off);              off += (((size_t)(2*NQ_+1)*DV_*4 + 255)/256)*256;
  float* addTab   = (float*)(ws + off);              off += (((size_t)(2*NQ_+1)*DV_*4 + 255)/256)*256;
  unsigned short* reads = (unsigned short*)(ws + off);

  hipMemsetAsync(accum, 0, 2*sizeof(float), stream);
  k_corr<<<dim3((NQ_+1+255)/256), dim3(256), 0, stream>>>(qw, mk, corrTab);
  k_ea<<<dim3((2*NQ_+1+RPB-1)/RPB), dim3(256), 0, stream>>>(qaw, ew, eb, aw, ab, eraseTab, addTab);
  k_scan<<<dim3(B_), dim3(256), 0, stream>>>(qd, qad, corrTab, eraseTab, addTab, mv0, reads);
  k_out<<<dim3(B_*S_/256), dim3(256), 0, stream>>>(reads, qd, qw, rw, rb, pw, pb, target, out, accum);
  k_fin<<<dim3(1), dim3(1), 0, stream>>>(accum, out);
}

// Round 2
// 428.233 us; speedup vs baseline: 1.0859x; 1.0859x over previous
//
#include <hip/hip_runtime.h>
#include <math.h>

#define B_   256
#define S_   512
#define NQ_  1000
#define MEM_ 20
#define DK_  50
#define DV_  200
#define FC_  50
#define RPB  8

static __device__ __forceinline__ unsigned short f2bf(float f){
  unsigned u = __float_as_uint(f);
  unsigned r = u + 0x7fffu + ((u >> 16) & 1u);   // round-to-nearest-even
  return (unsigned short)(r >> 16);
}
static __device__ __forceinline__ float bfhi(unsigned v){ return __uint_as_float(v & 0xffff0000u); }
static __device__ __forceinline__ float bflo(unsigned v){ return __uint_as_float(v << 16); }

// K1: corrTab[q][m] = softmax_m( q_embed_w[q] . memory_key[m] )   (20 floats/row, 80B, 16B-aligned)
__global__ void k_corr(const float* __restrict__ qw, const float* __restrict__ mk,
                       float* __restrict__ corrTab){
  int q = blockIdx.x*blockDim.x + threadIdx.x;
  if(q > NQ_) return;
  float qv[DK_];
  #pragma unroll
  for(int j=0;j<DK_;++j) qv[j] = qw[q*DK_+j];
  float s[MEM_]; float mx = -1e30f;
  #pragma unroll
  for(int m=0;m<MEM_;++m){
    float acc = 0.f;
    #pragma unroll
    for(int j=0;j<DK_;++j) acc = fmaf(qv[j], mk[m*DK_+j], acc);
    s[m] = acc; mx = fmaxf(mx, acc);
  }
  float sum = 0.f;
  #pragma unroll
  for(int m=0;m<MEM_;++m){ s[m] = expf(s[m]-mx); sum += s[m]; }
  float inv = 1.f/sum;
  #pragma unroll
  for(int m=0;m<MEM_;++m) corrTab[q*MEM_+m] = s[m]*inv;
}

// K2: eaTab[qa][d] = (sigmoid(qa_e@erase_w+eb)[d], tanh(qa_e@add_w+ab)[d]) interleaved float2
__global__ __launch_bounds__(256) void k_ea(const float* __restrict__ qaw,
      const float* __restrict__ ew, const float* __restrict__ eb,
      const float* __restrict__ aw, const float* __restrict__ ab,
      float2* __restrict__ eaTab){
  __shared__ float qa[RPB][DV_];
  int row0 = blockIdx.x*RPB;
  for(int i=threadIdx.x; i<RPB*DV_; i+=256){
    int r = i/DV_, c = i - r*DV_;
    int row = row0 + r;
    qa[r][c] = (row <= 2*NQ_) ? qaw[row*DV_+c] : 0.f;
  }
  __syncthreads();
  int d = threadIdx.x;
  if(d >= DV_) return;
  float accE[RPB], accA[RPB];
  #pragma unroll
  for(int r=0;r<RPB;++r){ accE[r] = eb[d]; accA[r] = ab[d]; }
  for(int j=0;j<DV_;++j){
    float we = ew[j*DV_+d], wa = aw[j*DV_+d];
    #pragma unroll
    for(int r=0;r<RPB;++r){
      float x = qa[r][j];
      accE[r] = fmaf(x, we, accE[r]);
      accA[r] = fmaf(x, wa, accA[r]);
    }
  }
  #pragma unroll
  for(int r=0;r<RPB;++r){
    int row = row0 + r;
    if(row <= 2*NQ_){
      eaTab[(size_t)row*DV_+d] = make_float2(1.f/(1.f+expf(-accE[r])), tanhf(accA[r]));
    }
  }
}

// K3: recurrence. One block per batch element, thread d owns Mv[0..19][d] in regs.
// ALL per-step operands via vector global loads (vmcnt only — no LDS/SMEM mixing):
//   q/qa: uniform-address dword loads, distance-2 prefetch
//   corr row: 5x float4 uniform loads, distance-1
//   erase/add: one coalesced float2 load, distance-1
__global__ __launch_bounds__(256) void k_scan(const int* __restrict__ qd,
    const int* __restrict__ qad,
    const float4* __restrict__ corr4,
    const float2* __restrict__ eaTab,
    const float* __restrict__ mv0,
    unsigned short* __restrict__ reads){
  const int b = blockIdx.x;
  const int d = threadIdx.x;
  const int dc = (d < DV_) ? d : DV_-1;     // clamp so inactive lanes stay uniform
  const bool act = (d < DV_);
  const int* __restrict__ qp  = qd  + b*S_;
  const int* __restrict__ qap = qad + b*S_;

  float Mv[MEM_];
  #pragma unroll
  for(int m=0;m<MEM_;++m) Mv[m] = mv0[m*DV_+dc];

  // pipeline init: q for t=0 and t=1; tables for t=0
  int q2  = qp[1];                 // index for t+1
  int qa2 = qap[1];
  int q1  = qp[0];
  int qa1 = qap[0];
  float4 c0 = corr4[q1*5+0], c1 = corr4[q1*5+1], c2 = corr4[q1*5+2],
         c3 = corr4[q1*5+3], c4 = corr4[q1*5+4];
  float2 ea = eaTab[(size_t)qa1*DV_ + dc];

  unsigned short* __restrict__ op = reads + (size_t)b*S_*DV_ + d;

  #pragma unroll 2
  for(int t=0;t<S_;++t){
    // q/qa for t+2 (addresses static -> issue immediately, 2 iters of slack)
    int t2 = (t+2 < S_) ? t+2 : S_-1;
    int q3 = qp[t2], qa3 = qap[t2];
    // tables for t+1 (1 iter of slack, vmcnt-selective waits)
    float4 n0 = corr4[q2*5+0], n1 = corr4[q2*5+1], n2 = corr4[q2*5+2],
           n3 = corr4[q2*5+3], n4 = corr4[q2*5+4];
    float2 ean = eaTab[(size_t)qa2*DV_ + dc];

    const float e = ea.x, a = ea.y;
    float rd = 0.f;
    #define UPD(cv, mi) \
      rd = fmaf(cv, Mv[mi], rd); \
      Mv[mi] = fmaf(cv, fmaf(-Mv[mi], e, a), Mv[mi]);
    UPD(c0.x, 0)  UPD(c0.y, 1)  UPD(c0.z, 2)  UPD(c0.w, 3)
    UPD(c1.x, 4)  UPD(c1.y, 5)  UPD(c1.z, 6)  UPD(c1.w, 7)
    UPD(c2.x, 8)  UPD(c2.y, 9)  UPD(c2.z,10)  UPD(c2.w,11)
    UPD(c3.x,12)  UPD(c3.y,13)  UPD(c3.z,14)  UPD(c3.w,15)
    UPD(c4.x,16)  UPD(c4.y,17)  UPD(c4.z,18)  UPD(c4.w,19)
    #undef UPD

    if(act) op[(size_t)t*DV_] = f2bf(rd);

    c0=n0; c1=n1; c2=n2; c3=n3; c4=n4; ea=ean;
    q2=q3; qa2=qa3;
  }
}

// K4: h = tanh([reads, q_e] @ read_w + rb); logit = h @ pw + pb; prob + masked BCE.
__global__ __launch_bounds__(256) void k_out(
    const unsigned short* __restrict__ reads,
    const int* __restrict__ qd,
    const float* __restrict__ qw,
    const float* __restrict__ rw, const float* __restrict__ rb,
    const float* __restrict__ pw, const float* __restrict__ pb,
    const float* __restrict__ target,
    float* __restrict__ out, float* __restrict__ accum){
  int row = blockIdx.x*256 + threadIdx.x;
  float acc[FC_];
  #pragma unroll
  for(int f=0;f<FC_;++f) acc[f] = rb[f];

  const uint4* xp = reinterpret_cast<const uint4*>(reads + (size_t)row*DV_);
  uint4 v = xp[0];
  #pragma unroll 1
  for(int blk=0; blk<DV_/8; ++blk){
    uint4 vn = xp[(blk+1 < DV_/8) ? blk+1 : blk];   // prefetch next 8 bf16
    float xv[8];
    xv[0]=bflo(v.x); xv[1]=bfhi(v.x); xv[2]=bflo(v.y); xv[3]=bfhi(v.y);
    xv[4]=bflo(v.z); xv[5]=bfhi(v.z); xv[6]=bflo(v.w); xv[7]=bfhi(v.w);
    const float* wb = rw + blk*8*FC_;
    #pragma unroll
    for(int k=0;k<8;++k){
      float xk = xv[k];
      const float* wr = wb + k*FC_;
      #pragma unroll
      for(int f=0;f<FC_;++f) acc[f] = fmaf(xk, wr[f], acc[f]);
    }
    v = vn;
  }

  int q = qd[row];
  const float2* qe2 = reinterpret_cast<const float2*>(qw + q*DK_);
  #pragma unroll 1
  for(int j2=0;j2<DK_/2;++j2){
    float2 x2 = qe2[j2];
    const float* wr = rw + (DV_ + 2*j2)*FC_;
    #pragma unroll
    for(int f=0;f<FC_;++f) acc[f] = fmaf(x2.x, wr[f], acc[f]);
    #pragma unroll
    for(int f=0;f<FC_;++f) acc[f] = fmaf(x2.y, wr[FC_+f], acc[f]);
  }

  float logit = pb[0];
  #pragma unroll
  for(int f=0;f<FC_;++f) logit = fmaf(pw[f], tanhf(acc[f]), logit);

  float prob = 1.f/(1.f+expf(-logit));
  out[1+row] = prob;

  float t = target[row];
  float bce = 0.f, cnt = 0.f;
  if(t >= 0.f){
    cnt = 1.f;
    bce = fmaxf(logit,0.f) - logit*t + log1pf(expf(-fabsf(logit)));
  }
  #pragma unroll
  for(int off=32; off>0; off>>=1){
    bce += __shfl_down(bce, off, 64);
    cnt += __shfl_down(cnt, off, 64);
  }
  if((threadIdx.x & 63) == 0){
    atomicAdd(accum,   bce);
    atomicAdd(accum+1, cnt);
  }
}

__global__ void k_fin(const float* __restrict__ accum, float* __restrict__ out){
  out[0] = accum[0] / fmaxf(accum[1], 1.f);
}

extern "C" void kernel_launch(void* const* d_in, const int* in_sizes, int n_in,
                              void* d_out, int out_size, void* d_ws, size_t ws_size,
                              hipStream_t stream){
  const int*   qd     = (const int*)d_in[0];
  const int*   qad    = (const int*)d_in[1];
  const float* target = (const float*)d_in[2];
  const float* qw     = (const float*)d_in[3];
  const float* qaw    = (const float*)d_in[4];
  const float* mk     = (const float*)d_in[5];
  const float* mv0    = (const float*)d_in[6];
  const float* ew     = (const float*)d_in[7];
  const float* eb     = (const float*)d_in[8];
  const float* aw     = (const float*)d_in[9];
  const float* ab     = (const float*)d_in[10];
  const float* rw     = (const float*)d_in[11];
  const float* rb     = (const float*)d_in[12];
  const float* pw     = (const float*)d_in[13];
  const float* pb     = (const float*)d_in[14];
  float* out = (float*)d_out;

  char* ws = (char*)d_ws;
  size_t off = 0;
  float* accum = (float*)(ws + off);                 off += 256;
  float* corrTab  = (float*)(ws + off);              off += (((size_t)(NQ_+1)*MEM_*4 + 255)/256)*256;
  float2* eaTab   = (float2*)(ws + off);             off += (((size_t)(2*NQ_+1)*DV_*8 + 255)/256)*256;
  unsigned short* reads = (unsigned short*)(ws + off);

  hipMemsetAsync(accum, 0, 2*sizeof(float), stream);
  k_corr<<<dim3((NQ_+1+255)/256), dim3(256), 0, stream>>>(qw, mk, corrTab);
  k_ea<<<dim3((2*NQ_+1+RPB-1)/RPB), dim3(256), 0, stream>>>(qaw, ew, eb, aw, ab, eaTab);
  k_scan<<<dim3(B_), dim3(256), 0, stream>>>(qd, qad, (const float4*)corrTab, (const float2*)eaTab, mv0, reads);
  k_out<<<dim3(B_*S_/256), dim3(256), 0, stream>>>(reads, qd, qw, rw, rb, pw, pb, target, out, accum);
  k_fin<<<dim3(1), dim3(1), 0, stream>>>(accum, out);
}